// Round 1
// baseline (126.509 us; speedup 1.0000x reference)
//
#include <hip/hip_runtime.h>

// Segment sum: out[s, f] = sum over rows r with seg[r]==s of memory[r, f].
// memory: [NELEMS, 128] f32, seg: sorted int (harness delivers integers as int32),
// out: [NSEG, 128] f32.

#define FEAT 128
#define F4 (FEAT / 4)          // 32 float4 per row
#define ROWLANES 8             // rows processed in parallel per block
#define THREADS (F4 * ROWLANES) // 256

__global__ void zero_kernel(float* __restrict__ out, int n) {
    int i = blockIdx.x * blockDim.x + threadIdx.x;
    if (i < n) out[i] = 0.0f;
}

__global__ __launch_bounds__(THREADS) void segsum_kernel(
        const float4* __restrict__ mem,   // [nelems, F4]
        const int* __restrict__ seg,      // [nelems], sorted
        float* __restrict__ out,          // [nseg, FEAT], pre-zeroed
        int nelems, int rows_per_block) {
    const int lane = threadIdx.x & (F4 - 1);  // float4 column 0..31
    const int rl   = threadIdx.x >> 5;        // row-lane 0..7

    long long r0 = (long long)blockIdx.x * rows_per_block;
    long long r1 = r0 + rows_per_block;
    if (r1 > nelems) r1 = nelems;
    if (r0 >= r1) return;

    float4 acc = make_float4(0.f, 0.f, 0.f, 0.f);
    int cur = -1;

    for (long long r = r0 + rl; r < r1; r += ROWLANES) {
        int s = seg[r];
        float4 v = mem[r * F4 + lane];
        if (s != cur) {
            if (cur >= 0) {
                float* o = out + (size_t)cur * FEAT + lane * 4;
                atomicAdd(o + 0, acc.x);
                atomicAdd(o + 1, acc.y);
                atomicAdd(o + 2, acc.z);
                atomicAdd(o + 3, acc.w);
            }
            cur = s;
            acc = v;
        } else {
            acc.x += v.x;
            acc.y += v.y;
            acc.z += v.z;
            acc.w += v.w;
        }
    }
    if (cur >= 0) {
        float* o = out + (size_t)cur * FEAT + lane * 4;
        atomicAdd(o + 0, acc.x);
        atomicAdd(o + 1, acc.y);
        atomicAdd(o + 2, acc.z);
        atomicAdd(o + 3, acc.w);
    }
}

extern "C" void kernel_launch(void* const* d_in, const int* in_sizes, int n_in,
                              void* d_out, int out_size, void* d_ws, size_t ws_size,
                              hipStream_t stream) {
    const float4* mem = (const float4*)d_in[0];
    const int* seg = (const int*)d_in[1];
    float* out = (float*)d_out;

    int nelems = in_sizes[1];   // 1,000,000

    // Zero the (poisoned) output first.
    {
        int zb = (out_size + 255) / 256;
        zero_kernel<<<zb, 256, 0, stream>>>(out, out_size);
    }

    const int grid = 2048;
    int rows_per_block = (nelems + grid - 1) / grid;
    segsum_kernel<<<grid, THREADS, 0, stream>>>(mem, seg, out, nelems,
                                                rows_per_block);
}

// Round 2
// 96.813 us; speedup vs baseline: 1.3067x; 1.3067x over previous
//
#include <hip/hip_runtime.h>

// Segment sum: out[s, f] = sum over rows r with seg[r]==s of memory[r, f].
// memory: [NELEMS, 128] f32, seg: [NELEMS] int32 SORTED ascending,
// out: [NSEG, 128] f32.
//
// Plan:
//  kernel 1: scan seg -> starts[s] = first row index with seg[i] >= s,
//            for s = 0..NSEG (NSEG+1 entries, in d_ws). Exact because sorted.
//  kernel 2: one block per segment; branch-free unroll-4 streaming of the
//            segment's rows; LDS reduce across row-lanes; one coalesced
//            float4 store per segment. No atomics, no zeroing pass.

#define FEAT 128
#define F4 (FEAT / 4)            // 32 float4 per row
#define ROWLANES 8               // row-lanes per block
#define THREADS (F4 * ROWLANES)  // 256

__global__ void boundaries_kernel(const int* __restrict__ seg,
                                  int* __restrict__ starts,
                                  int nelems, int nseg) {
    int i = blockIdx.x * blockDim.x + threadIdx.x;
    if (i >= nelems) return;
    int cur = seg[i];
    int prev = (i == 0) ? -1 : seg[i - 1];
    // Each boundary value s in (prev, cur] starts at row i. Sorted input ->
    // each starts[s] is written by exactly one thread.
    for (int s = prev + 1; s <= cur; ++s) starts[s] = i;
    if (i == nelems - 1) {
        for (int s = cur + 1; s <= nseg; ++s) starts[s] = nelems;
    }
}

__device__ __forceinline__ void acc4(float4& a, const float4 v) {
    a.x += v.x; a.y += v.y; a.z += v.z; a.w += v.w;
}

__global__ __launch_bounds__(THREADS) void segsum_kernel(
        const float4* __restrict__ mem,     // [nelems, F4]
        const int* __restrict__ starts,     // [nseg+1]
        float4* __restrict__ out) {         // [nseg, F4]
    const int b    = blockIdx.x;
    const int lane = threadIdx.x & (F4 - 1);  // float4 column 0..31
    const int rl   = threadIdx.x >> 5;        // row-lane 0..7

    const int start = starts[b];
    const int end   = starts[b + 1];

    float4 a0 = make_float4(0.f, 0.f, 0.f, 0.f);
    float4 a1 = make_float4(0.f, 0.f, 0.f, 0.f);
    float4 a2 = make_float4(0.f, 0.f, 0.f, 0.f);
    float4 a3 = make_float4(0.f, 0.f, 0.f, 0.f);

    int r = start + rl;
    // Unroll-4: 4 independent 16B loads in flight per thread.
    for (; r + 3 * ROWLANES < end; r += 4 * ROWLANES) {
        float4 v0 = mem[(size_t)r * F4 + lane];
        float4 v1 = mem[(size_t)(r + ROWLANES) * F4 + lane];
        float4 v2 = mem[(size_t)(r + 2 * ROWLANES) * F4 + lane];
        float4 v3 = mem[(size_t)(r + 3 * ROWLANES) * F4 + lane];
        acc4(a0, v0); acc4(a1, v1); acc4(a2, v2); acc4(a3, v3);
    }
    for (; r < end; r += ROWLANES) {
        acc4(a0, mem[(size_t)r * F4 + lane]);
    }
    acc4(a0, a1); acc4(a2, a3); acc4(a0, a2);

    // Reduce across the 8 row-lanes via LDS.
    __shared__ float4 red[ROWLANES][F4];
    red[rl][lane] = a0;
    __syncthreads();
    if (rl == 0) {
        float4 s = red[0][lane];
        for (int k = 1; k < ROWLANES; ++k) acc4(s, red[k][lane]);
        out[(size_t)b * F4 + lane] = s;  // covers empty segments (writes zeros)
    }
}

extern "C" void kernel_launch(void* const* d_in, const int* in_sizes, int n_in,
                              void* d_out, int out_size, void* d_ws, size_t ws_size,
                              hipStream_t stream) {
    const float4* mem = (const float4*)d_in[0];
    const int* seg = (const int*)d_in[1];
    float4* out = (float4*)d_out;
    int* starts = (int*)d_ws;           // NSEG+1 ints

    const int nelems = in_sizes[1];     // 1,000,000
    const int nseg = out_size / FEAT;   // 1024

    int bblocks = (nelems + 255) / 256;
    boundaries_kernel<<<bblocks, 256, 0, stream>>>(seg, starts, nelems, nseg);

    segsum_kernel<<<nseg, THREADS, 0, stream>>>(mem, starts, out);
}

// Round 3
// 84.650 us; speedup vs baseline: 1.4945x; 1.1437x over previous
//
#include <hip/hip_runtime.h>

// Segment sum: out[s, f] = sum over rows r with seg[r]==s of memory[r, f].
// memory: [NELEMS, 128] f32, seg: [NELEMS] int32 SORTED ascending,
// out: [NSEG, 128] f32.
//
//  kernel 1: scan seg -> starts[s] (NSEG+1 entries in d_ws). Exact (sorted).
//  kernel 2: one block (512 thr, 16 row-lanes) per segment; branch-free
//            unroll-4 nontemporal streaming; LDS reduce; one float4 store.
//            No atomics, no zeroing pass (every out row written).

#define FEAT 128
#define F4 (FEAT / 4)             // 32 float4 per row
#define ROWLANES 16               // row-lanes per block
#define THREADS (F4 * ROWLANES)   // 512

typedef float f32x4 __attribute__((ext_vector_type(4)));

__global__ void boundaries_kernel(const int* __restrict__ seg,
                                  int* __restrict__ starts,
                                  int nelems, int nseg) {
    int i = blockIdx.x * blockDim.x + threadIdx.x;
    if (i >= nelems) return;
    int cur = seg[i];
    int prev = (i == 0) ? -1 : seg[i - 1];
    for (int s = prev + 1; s <= cur; ++s) starts[s] = i;
    if (i == nelems - 1) {
        for (int s = cur + 1; s <= nseg; ++s) starts[s] = nelems;
    }
}

__global__ __launch_bounds__(THREADS, 8) void segsum_kernel(
        const f32x4* __restrict__ mem,      // [nelems, F4]
        const int* __restrict__ starts,     // [nseg+1]
        f32x4* __restrict__ out) {          // [nseg, F4]
    const int b    = blockIdx.x;
    const int lane = threadIdx.x & (F4 - 1);  // float4 column 0..31
    const int rl   = threadIdx.x >> 5;        // row-lane 0..15

    const int start = starts[b];
    const int end   = starts[b + 1];

    f32x4 a0 = (f32x4)0.f, a1 = (f32x4)0.f, a2 = (f32x4)0.f, a3 = (f32x4)0.f;

    int r = start + rl;
    for (; r + 3 * ROWLANES < end; r += 4 * ROWLANES) {
        f32x4 v0 = __builtin_nontemporal_load(&mem[(size_t)r * F4 + lane]);
        f32x4 v1 = __builtin_nontemporal_load(&mem[(size_t)(r + ROWLANES) * F4 + lane]);
        f32x4 v2 = __builtin_nontemporal_load(&mem[(size_t)(r + 2 * ROWLANES) * F4 + lane]);
        f32x4 v3 = __builtin_nontemporal_load(&mem[(size_t)(r + 3 * ROWLANES) * F4 + lane]);
        a0 += v0; a1 += v1; a2 += v2; a3 += v3;
    }
    for (; r < end; r += ROWLANES) {
        a0 += __builtin_nontemporal_load(&mem[(size_t)r * F4 + lane]);
    }
    a0 += a1; a2 += a3; a0 += a2;

    // Reduce across the 16 row-lanes via LDS (two stages).
    __shared__ f32x4 red[ROWLANES][F4];
    red[rl][lane] = a0;
    __syncthreads();
    if (rl < 4) {
        f32x4 s = red[rl][lane] + red[rl + 4][lane] +
                  red[rl + 8][lane] + red[rl + 12][lane];
        red[rl][lane] = s;
    }
    __syncthreads();
    if (rl == 0) {
        f32x4 s = red[0][lane] + red[1][lane] + red[2][lane] + red[3][lane];
        out[(size_t)b * F4 + lane] = s;  // covers empty segments (zeros)
    }
}

extern "C" void kernel_launch(void* const* d_in, const int* in_sizes, int n_in,
                              void* d_out, int out_size, void* d_ws, size_t ws_size,
                              hipStream_t stream) {
    const f32x4* mem = (const f32x4*)d_in[0];
    const int* seg = (const int*)d_in[1];
    f32x4* out = (f32x4*)d_out;
    int* starts = (int*)d_ws;           // NSEG+1 ints

    const int nelems = in_sizes[1];     // 1,000,000
    const int nseg = out_size / FEAT;   // 1024

    int bblocks = (nelems + 255) / 256;
    boundaries_kernel<<<bblocks, 256, 0, stream>>>(seg, starts, nelems, nseg);

    segsum_kernel<<<nseg, THREADS, 0, stream>>>(mem, starts, out);
}

// Round 4
// 81.375 us; speedup vs baseline: 1.5547x; 1.0402x over previous
//
#include <hip/hip_runtime.h>

// Segment sum: out[s, f] = sum over rows r with seg[r]==s of memory[r, f].
// memory: [NELEMS, 128] f32, seg: [NELEMS] int32 SORTED ascending,
// out: [NSEG, 128] f32.
//
// Single fused kernel, one block per segment (512 thr = 8 waves; 1024 blocks
// x 8 waves = 32 waves/CU, whole grid co-resident):
//   prologue: wave 0 finds [start,end) via 32-ary lower_bound on seg
//             (two 32-lane halves search b and b+1; 4 probe rounds + final),
//             result broadcast through LDS.
//   body:     branch-free unroll-4 nontemporal float4 streaming, LDS reduce
//             across 16 row-lanes, one coalesced float4 store per segment.
//   No atomics, no zeroing pass (every out row is written, incl. empty segs).

#define FEAT 128
#define F4 (FEAT / 4)             // 32 float4 per row
#define ROWLANES 16               // row-lanes per block
#define THREADS (F4 * ROWLANES)   // 512

typedef float f32x4 __attribute__((ext_vector_type(4)));

__global__ __launch_bounds__(THREADS, 8) void segsum_fused(
        const f32x4* __restrict__ mem,    // [nelems, F4]
        const int* __restrict__ seg,      // [nelems], sorted ascending
        f32x4* __restrict__ out,          // [nseg, F4]
        int nelems) {
    const int b    = blockIdx.x;
    const int lane = threadIdx.x & (F4 - 1);  // float4 column 0..31
    const int rl   = threadIdx.x >> 5;        // row-lane 0..15

    __shared__ int sb[2];                     // {start, end}

    if (threadIdx.x < 64) {                   // wave 0 only
        const int half = threadIdx.x >> 5;    // 0: lower_bound(b), 1: lower_bound(b+1)
        const int j    = threadIdx.x & 31;
        const int t    = b + half;

        int lo = 0, len = nelems;
        #pragma unroll
        for (int round = 0; round < 4; ++round) {
            int pos = lo + (int)(((long long)j * len) >> 5);
            int v = seg[pos];
            unsigned long long m = __ballot(v < t);
            unsigned mh = half ? (unsigned)(m >> 32) : (unsigned)(m & 0xffffffffull);
            int c = __popc(mh);
            int pcm1 = lo + (int)(((long long)(c - 1) * len) >> 5);
            int pc   = (c < 32) ? (lo + (int)(((long long)c * len) >> 5)) : (lo + len);
            int newlo = (c > 0) ? pcm1 : lo;
            int newhi = (c > 0) ? pc : lo;    // c==0 -> seg[lo] >= t -> lb == lo
            lo = newlo;
            len = newhi - newlo;
        }
        // final: len <= 32
        int v = (j < len) ? seg[lo + j] : 0x7fffffff;
        unsigned long long m = __ballot(v < t);
        unsigned mh = half ? (unsigned)(m >> 32) : (unsigned)(m & 0xffffffffull);
        if (j == 0) sb[half] = lo + __popc(mh);
    }
    __syncthreads();

    const int start = sb[0];
    const int end   = sb[1];

    f32x4 a0 = (f32x4)0.f, a1 = (f32x4)0.f, a2 = (f32x4)0.f, a3 = (f32x4)0.f;

    int r = start + rl;
    for (; r + 3 * ROWLANES < end; r += 4 * ROWLANES) {
        f32x4 v0 = __builtin_nontemporal_load(&mem[(size_t)r * F4 + lane]);
        f32x4 v1 = __builtin_nontemporal_load(&mem[(size_t)(r + ROWLANES) * F4 + lane]);
        f32x4 v2 = __builtin_nontemporal_load(&mem[(size_t)(r + 2 * ROWLANES) * F4 + lane]);
        f32x4 v3 = __builtin_nontemporal_load(&mem[(size_t)(r + 3 * ROWLANES) * F4 + lane]);
        a0 += v0; a1 += v1; a2 += v2; a3 += v3;
    }
    for (; r < end; r += ROWLANES) {
        a0 += __builtin_nontemporal_load(&mem[(size_t)r * F4 + lane]);
    }
    a0 += a1; a2 += a3; a0 += a2;

    // Reduce across the 16 row-lanes via LDS (two stages).
    __shared__ f32x4 red[ROWLANES][F4];
    red[rl][lane] = a0;
    __syncthreads();
    if (rl < 4) {
        red[rl][lane] = red[rl][lane] + red[rl + 4][lane] +
                        red[rl + 8][lane] + red[rl + 12][lane];
    }
    __syncthreads();
    if (rl == 0) {
        f32x4 s = red[0][lane] + red[1][lane] + red[2][lane] + red[3][lane];
        out[(size_t)b * F4 + lane] = s;   // covers empty segments (zeros)
    }
}

extern "C" void kernel_launch(void* const* d_in, const int* in_sizes, int n_in,
                              void* d_out, int out_size, void* d_ws, size_t ws_size,
                              hipStream_t stream) {
    const f32x4* mem = (const f32x4*)d_in[0];
    const int* seg = (const int*)d_in[1];
    f32x4* out = (f32x4*)d_out;

    const int nelems = in_sizes[1];     // 1,000,000
    const int nseg = out_size / FEAT;   // 1024

    segsum_fused<<<nseg, THREADS, 0, stream>>>(mem, seg, out, nelems);
}